// Round 2
// baseline (145.257 us; speedup 1.0000x reference)
//
#include <hip/hip_runtime.h>
#include <math.h>

#define N_NODES 1024
#define N_EVAL 131072
#define NUM_POLES 8
#define PI_D 3.14159265358979323846

// ws layout: float nodes_f[1024] | float w_f[1024] | float wv_f[1024]
//
// Closed-form barycentric weights for Chebyshev points of the 2nd kind
// x_j = cos(pi*j/n), n = N_NODES-1:
//   1 / prod_{i!=j}(x_j - x_i) = (-1)^j * delta_j * 2^(n-1)/n,  delta = 1/2 at ends.
// The reference's -max and /|w[0]| normalizations are uniform scalings that
// cancel exactly in num/den, so we only need:
//   w_j = (-1)^j * delta_j * prod_m((x_j - pr_m)^2 + pi_m^2)
__global__ void wk_setup(const float* __restrict__ values,
                         const float* __restrict__ poles_real,
                         const float* __restrict__ poles_imag,
                         float* __restrict__ nodes_f,
                         float* __restrict__ w_f,
                         float* __restrict__ wv_f) {
    const int j = threadIdx.x;
    const double nd = cos(PI_D * (double)j / (double)(N_NODES - 1));
    double prod = (j == 0 || j == N_NODES - 1) ? 0.5 : 1.0;
#pragma unroll
    for (int m = 0; m < NUM_POLES; ++m) {
        double dr = nd - (double)poles_real[m];
        double di = (double)poles_imag[m];
        prod *= dr * dr + di * di;
    }
    if (j & 1) prod = -prod;
    const float wf = (float)prod;
    nodes_f[j] = (float)nd;
    w_f[j] = wf;
    wv_f[j] = (float)(prod * (double)values[j]);
}

// Eval: 1 point/thread, branchless inner loop. Exact node hits (d==0) poison
// the accumulators with NaN via rcp(0)=inf -> fma(-0,inf,1)=NaN; the rare
// fix-up loop after the main loop handles them (reference semantics: exact-hit
// column reduces to v_j).
__global__ __launch_bounds__(256) void eval_kernel(
    const float* __restrict__ x_eval,
    const float* __restrict__ nodes_f,
    const float* __restrict__ w_f,
    const float* __restrict__ wv_f,
    float* __restrict__ out) {
    __shared__ __align__(16) float s_n[N_NODES];
    __shared__ __align__(16) float s_w[N_NODES];
    __shared__ __align__(16) float s_v[N_NODES];
    const int t = threadIdx.x;
    for (int k = t; k < N_NODES; k += 256) {
        s_n[k] = nodes_f[k];
        s_w[k] = w_f[k];
        s_v[k] = wv_f[k];
    }
    __syncthreads();

    const int i = blockIdx.x * 256 + t;
    const float x = x_eval[i];

    float num0 = 0.0f, den0 = 0.0f;
    float num1 = 0.0f, den1 = 0.0f;

    const float4* n4 = (const float4*)s_n;
    const float4* w4 = (const float4*)s_w;
    const float4* v4 = (const float4*)s_v;

#define BODY(C, NUM, DEN)                                                  \
    {                                                                      \
        float d = x - an.C;                                                \
        float r = __builtin_amdgcn_rcpf(d);                                \
        r = fmaf(r, fmaf(-d, r, 1.0f), r); /* 1 Newton step */             \
        NUM = fmaf(av.C, r, NUM);                                          \
        DEN = fmaf(aw.C, r, DEN);                                          \
    }

#pragma unroll 4
    for (int j4 = 0; j4 < N_NODES / 4; ++j4) {
        float4 an = n4[j4];
        float4 aw = w4[j4];
        float4 av = v4[j4];
        BODY(x, num0, den0)
        BODY(y, num1, den1)
        BODY(z, num0, den0)
        BODY(w, num1, den1)
    }
#undef BODY

    float res = (num0 + num1) / (den0 + den1);

    if (__builtin_expect(__builtin_isnan(res), 0)) {
        // Exact hit: reference zeroes all non-hit rows of this column and
        // sets hit rows to 1 -> result = sum(hit wv)/sum(hit w) = v_j.
        float hn = 0.0f, hd = 0.0f;
        for (int j = 0; j < N_NODES; ++j) {
            if (s_n[j] == x) { hn += s_v[j]; hd += s_w[j]; }
        }
        res = hn / hd;
    }
    out[i] = res;
}

extern "C" void kernel_launch(void* const* d_in, const int* in_sizes, int n_in,
                              void* d_out, int out_size, void* d_ws, size_t ws_size,
                              hipStream_t stream) {
    const float* x_eval     = (const float*)d_in[0];
    const float* values     = (const float*)d_in[1];
    const float* poles_real = (const float*)d_in[2];
    const float* poles_imag = (const float*)d_in[3];
    float* out = (float*)d_out;

    float* nodes_f = (float*)d_ws;
    float* w_f     = nodes_f + N_NODES;
    float* wv_f    = w_f + N_NODES;

    wk_setup<<<1, N_NODES, 0, stream>>>(values, poles_real, poles_imag,
                                        nodes_f, w_f, wv_f);
    eval_kernel<<<N_EVAL / 256, 256, 0, stream>>>(x_eval, nodes_f, w_f, wv_f, out);
}

// Round 3
// 130.284 us; speedup vs baseline: 1.1149x; 1.1149x over previous
//
#include <hip/hip_runtime.h>
#include <math.h>

#define N_NODES 1024
#define N_EVAL 131072
#define NUM_POLES 8
#define PI_D 3.14159265358979323846

#define CHUNKS 4
#define CHUNK_N 256    // nodes per lane-quad chunk
#define CHUNK_PAD 260  // padded LDS stride (floats): chunk bases land on distinct banks

// ws layout: float nodes_f[1024] | float w_f[1024] | float wv_f[1024]
//
// Closed-form barycentric weights for Chebyshev points of the 2nd kind
// x_j = cos(pi*j/n), n = N_NODES-1:
//   1 / prod_{i!=j}(x_j - x_i) = (-1)^j * delta_j * 2^(n-1)/n,  delta = 1/2 at ends.
// Uniform scalings (2^(n-1)/n, exp(-max), /|w[0]|) cancel in num/den, so:
//   w_j = (-1)^j * delta_j * prod_m((x_j - pr_m)^2 + pi_m^2)
__global__ void wk_setup(const float* __restrict__ values,
                         const float* __restrict__ poles_real,
                         const float* __restrict__ poles_imag,
                         float* __restrict__ nodes_f,
                         float* __restrict__ w_f,
                         float* __restrict__ wv_f) {
    const int j = threadIdx.x;
    const double nd = cos(PI_D * (double)j / (double)(N_NODES - 1));
    double prod = (j == 0 || j == N_NODES - 1) ? 0.5 : 1.0;
#pragma unroll
    for (int m = 0; m < NUM_POLES; ++m) {
        double dr = nd - (double)poles_real[m];
        double di = (double)poles_imag[m];
        prod *= dr * dr + di * di;
    }
    if (j & 1) prod = -prod;
    nodes_f[j] = (float)nd;
    w_f[j] = (float)prod;
    wv_f[j] = (float)(prod * (double)values[j]);
}

// Eval: lane quad (4 threads) per point; each thread sums a 256-node chunk,
// combine via shfl_xor. 2048 blocks -> 8 blocks/CU -> 8 waves/SIMD.
// Batched reciprocal: r = rcp(dx*dy); 1/dx = r*dy; 1/dy = r*dx (halves trans
// pressure). Exact node hits (d==0) poison accumulators with inf/NaN; rare
// fix-up scan afterwards (reference: exact-hit column reduces to v_j).
__global__ __launch_bounds__(256, 8) void eval_kernel(
    const float* __restrict__ x_eval,
    const float* __restrict__ nodes_f,
    const float* __restrict__ w_f,
    const float* __restrict__ wv_f,
    float* __restrict__ out) {
    __shared__ __align__(16) float s_n[CHUNKS * CHUNK_PAD];
    __shared__ __align__(16) float s_w[CHUNKS * CHUNK_PAD];
    __shared__ __align__(16) float s_v[CHUNKS * CHUNK_PAD];
    const int t = threadIdx.x;
#pragma unroll
    for (int it = 0; it < 4; ++it) {
        const int k = it * 256 + t;
        const int idx = it * CHUNK_PAD + t;
        s_n[idx] = nodes_f[k];
        s_w[idx] = w_f[k];
        s_v[idx] = wv_f[k];
    }
    __syncthreads();

    const int p = (blockIdx.x << 6) + (t >> 2);  // 64 points per block
    const int c = t & 3;                         // chunk id within quad
    const float x = x_eval[p];

    const float4* n4 = (const float4*)(s_n + c * CHUNK_PAD);
    const float4* w4 = (const float4*)(s_w + c * CHUNK_PAD);
    const float4* v4 = (const float4*)(s_v + c * CHUNK_PAD);

    float num0 = 0.0f, den0 = 0.0f;
    float num1 = 0.0f, den1 = 0.0f;

#pragma unroll 2
    for (int q = 0; q < CHUNK_N / 4; ++q) {
        const float4 an = n4[q];
        const float4 aw = w4[q];
        const float4 av = v4[q];
        const float dx = x - an.x;
        const float dy = x - an.y;
        const float dz = x - an.z;
        const float dw = x - an.w;
        const float p0 = dx * dy;
        const float p1 = dz * dw;
        const float r0 = __builtin_amdgcn_rcpf(p0);
        const float r1 = __builtin_amdgcn_rcpf(p1);
        const float rx = r0 * dy;
        const float ry = r0 * dx;
        const float rz = r1 * dw;
        const float rw = r1 * dz;
        num0 = fmaf(av.x, rx, num0);
        den0 = fmaf(aw.x, rx, den0);
        num1 = fmaf(av.y, ry, num1);
        den1 = fmaf(aw.y, ry, den1);
        num0 = fmaf(av.z, rz, num0);
        den0 = fmaf(aw.z, rz, den0);
        num1 = fmaf(av.w, rw, num1);
        den1 = fmaf(aw.w, rw, den1);
    }

    float num = num0 + num1;
    float den = den0 + den1;
    num += __shfl_xor(num, 1);
    den += __shfl_xor(den, 1);
    num += __shfl_xor(num, 2);
    den += __shfl_xor(den, 2);
    float res = num / den;

    if (c == 0) {
        if (__builtin_expect(__builtin_isnan(res), 0)) {
            // Exact hit: result = sum(hit wv)/sum(hit w) = v_j.
            float hn = 0.0f, hd = 0.0f;
            for (int cc = 0; cc < CHUNKS; ++cc) {
                for (int j = 0; j < CHUNK_N; ++j) {
                    const int idx = cc * CHUNK_PAD + j;
                    if (s_n[idx] == x) { hn += s_v[idx]; hd += s_w[idx]; }
                }
            }
            res = hn / hd;
        }
        out[p] = res;
    }
}

extern "C" void kernel_launch(void* const* d_in, const int* in_sizes, int n_in,
                              void* d_out, int out_size, void* d_ws, size_t ws_size,
                              hipStream_t stream) {
    const float* x_eval     = (const float*)d_in[0];
    const float* values     = (const float*)d_in[1];
    const float* poles_real = (const float*)d_in[2];
    const float* poles_imag = (const float*)d_in[3];
    float* out = (float*)d_out;

    float* nodes_f = (float*)d_ws;
    float* w_f     = nodes_f + N_NODES;
    float* wv_f    = w_f + N_NODES;

    wk_setup<<<1, N_NODES, 0, stream>>>(values, poles_real, poles_imag,
                                        nodes_f, w_f, wv_f);
    eval_kernel<<<N_EVAL / 64, 256, 0, stream>>>(x_eval, nodes_f, w_f, wv_f, out);
}